// Round 2
// baseline (2295.176 us; speedup 1.0000x reference)
//
#include <hip/hip_runtime.h>
#include <cstdint>

typedef __attribute__((ext_vector_type(8))) short short8;
typedef __attribute__((ext_vector_type(4))) float floatx4;
typedef unsigned int uint32;

typedef const void __attribute__((address_space(1)))* gcptr;
typedef void __attribute__((address_space(3)))* lptr;

// ---------------- problem dims ----------------
constexpr int Bn = 8, Sn = 1024, Dn = 1024, Hn = 4096;
constexpr uint32 KTOP = 1024u * 1024u;   // min(TOP_K*S, S*H) = 2^20
// 27-bit compact key space: e = clamp(skey(v) - SKBASE, 0, 2^27-1)
// covers score values in (2^-9, 128) exactly; bin = e>>14 (8192), rem = e&0x3FFF (16384)
constexpr uint32 SKBASE = 0xBB000000u;   // skey of +2^-9
constexpr uint32 EMAX = (1u << 27) - 1u;

// ---------------- workspace layout (bytes) ----------------
constexpr size_t NX  = (size_t)Bn * Sn * Dn;   // 8388608
constexpr size_t NW1 = (size_t)Hn * Dn;        // 4194304
constexpr size_t NW2 = (size_t)Hn * Hn;        // 16777216
constexpr size_t NRS = (size_t)Bn * Sn * Hn;   // 33554432

constexpr size_t OFF_XH   = 0;                         // 16 MB  (live: G1,G3)
constexpr size_t OFF_XL   = OFF_XH  + 2 * NX;          // 16 MB  (G1; then DWNW bf16)
constexpr size_t OFF_W1H  = OFF_XL  + 2 * NX;          // 8 MB   (G1; then UPW bf16)
constexpr size_t OFF_W1L  = OFF_W1H + 2 * NW1;         // 8 MB   (G1; then MODW bf16)
constexpr size_t OFF_W2H  = OFF_W1L + 2 * NW1;         // 32 MB  (G2/G2b)
constexpr size_t OFF_W2L  = OFF_W2H + 2 * NW2;         // 32 MB  (G2/G2b)
constexpr size_t OFF_RSH  = OFF_W2L + 2 * NW2;         // 64 MB  (G1->G2; then HBUF)
constexpr size_t OFF_RSL  = OFF_RSH + 2 * NRS;         // 64 MB  (G1->G2)
constexpr size_t OFF_HIST = OFF_RSL + 2 * NRS;         // 8 x 8192 u32   (zeroed)
constexpr size_t OFF_HIST2= OFF_HIST + (size_t)Bn * 8192 * 4;   // 8 x 16384 u32 (zeroed)
constexpr size_t OFF_HMAX = OFF_HIST2+ (size_t)Bn * 16384 * 4;  // 8 x 4096 u32  (zeroed)
constexpr size_t OFF_BSEL = OFF_HMAX + (size_t)Bn * Hn * 4;     // 8 x 4096 f32
constexpr size_t OFF_MASK = OFF_BSEL + (size_t)Bn * Hn * 4;     // 8 x 4096 u32
constexpr size_t OFF_META = OFF_MASK + (size_t)Bn * Hn * 4;     // 32 u32
constexpr size_t WS_SMALL = OFF_META + 4096;           // ~241.2 MB
constexpr size_t OFF_KEYS = WS_SMALL;                  // 128 MB (LARGE only)
constexpr size_t WS_LARGE = OFF_KEYS + 4 * NRS;        // ~369.2 MB
constexpr size_t ZERO_BYTES = OFF_BSEL - OFF_HIST;     // hist + hist2 + hmax

// ---------------- helpers ----------------
__device__ __forceinline__ ushort f2bf(float f) {        // fp32 -> bf16 RNE
  uint32 u = __float_as_uint(f);
  u += 0x7fffu + ((u >> 16) & 1u);
  return (ushort)(u >> 16);
}
__device__ __forceinline__ float bf2f(ushort h) {
  return __uint_as_float(((uint32)h) << 16);
}
__device__ __forceinline__ uint32 skey(float v) {        // monotone fp32 -> u32 key
  uint32 u = __float_as_uint(v);
  return (u & 0x80000000u) ? ~u : (u | 0x80000000u);
}
__device__ __forceinline__ uint32 ekey(uint32 key) {     // 27-bit compact key
  if (key <= SKBASE) return 0u;
  uint32 d = key - SKBASE;
  return d > EMAX ? EMAX : d;
}
__device__ __forceinline__ void g2l(const ushort* src, ushort* dst) {
  __builtin_amdgcn_global_load_lds((gcptr)src, (lptr)dst, 16, 0, 0);
}
// stage one 128x32 bf16 tile (8 KB) via global_load_lds width=16.
// LDS dest is wave-uniform base + lane*16 (m104/m108 rule) -> unpadded row-major layout.
__device__ __forceinline__ void stage_tile(ushort* lds, const ushort* gbase, int ldg, int tid) {
  const int w = tid >> 6;
  const int c0 = tid, c1 = tid + 256;
  g2l(gbase + (size_t)(c0 >> 2) * ldg + (c0 & 3) * 8, lds + (size_t)(w * 64) * 8);
  g2l(gbase + (size_t)(c1 >> 2) * ldg + (c1 & 3) * 8, lds + (size_t)(256 + w * 64) * 8);
}
// same, but per-row source select between mod_w / up_w via mask (per-lane global address ok)
__device__ __forceinline__ void stage_tile_sel(ushort* lds, const ushort* upw,
                                               const ushort* modw, const uint32* bm,
                                               int n0, int k0, int ldg, int tid) {
  const int w = tid >> 6;
  const int c0 = tid, c1 = tid + 256;
  const int r0 = n0 + (c0 >> 2), r1 = n0 + (c1 >> 2);
  const ushort* s0 = (bm[r0] ? modw : upw) + (size_t)r0 * ldg + k0 + (c0 & 3) * 8;
  const ushort* s1 = (bm[r1] ? modw : upw) + (size_t)r1 * ldg + k0 + (c1 & 3) * 8;
  g2l(s0, lds + (size_t)(w * 64) * 8);
  g2l(s1, lds + (size_t)(256 + w * 64) * 8);
}

// ---------------- conversion kernels ----------------
__global__ __launch_bounds__(256) void cvt_split_k(const float4* __restrict__ x,
                                                   ushort* __restrict__ hi,
                                                   ushort* __restrict__ lo, int n4) {
  int stride = gridDim.x * 256;
  for (int i = blockIdx.x * 256 + threadIdx.x; i < n4; i += stride) {
    float4 v = x[i];
    ushort h0 = f2bf(v.x), h1 = f2bf(v.y), h2 = f2bf(v.z), h3 = f2bf(v.w);
    ushort4 hv; hv.x = h0; hv.y = h1; hv.z = h2; hv.w = h3;
    *(ushort4*)(hi + (size_t)i * 4) = hv;
    ushort4 lv;
    lv.x = f2bf(v.x - bf2f(h0)); lv.y = f2bf(v.y - bf2f(h1));
    lv.z = f2bf(v.z - bf2f(h2)); lv.w = f2bf(v.w - bf2f(h3));
    *(ushort4*)(lo + (size_t)i * 4) = lv;
  }
}
__global__ __launch_bounds__(256) void cvt_single_k(const float4* __restrict__ x,
                                                    ushort* __restrict__ hi, int n4) {
  int stride = gridDim.x * 256;
  for (int i = blockIdx.x * 256 + threadIdx.x; i < n4; i += stride) {
    float4 v = x[i];
    ushort4 hv; hv.x = f2bf(v.x); hv.y = f2bf(v.y); hv.z = f2bf(v.z); hv.w = f2bf(v.w);
    *(ushort4*)(hi + (size_t)i * 4) = hv;
  }
}
__global__ __launch_bounds__(256) void zero_out_k(float* __restrict__ o, int n) {
  int i = blockIdx.x * 256 + threadIdx.x;
  if (i < n) o[i] = 0.f;
}

// ---------------- GEMM: C[m,n] = sum_k A[m,k]*B[n,k] (+epilogue) ----------------
// 128x128 tile, BK=32, 4 waves (2x2 of 64x64), mfma_f32_16x16x32_bf16.
// SPLIT: A,B given as hi+lo bf16 pairs; acc += Ah*Bh + Ah*Bl + Al*Bh (near-fp32 product).
// SELB:  B rows staged per-row from (mask ? modw : upw).
constexpr int EPI_RELU = 0;    // out: rs_hi/rs_lo bf16 split of relu(acc+bias[n])
constexpr int EPI_SCORE = 1;   // hist/colmax (+optional key store) of acc+bias[n]
constexpr int EPI_REFINE = 2;  // boundary-bucket remainder histogram (bit-exact re-run of SCORE)
constexpr int EPI_SILU = 3;    // out: bf16 silu(acc+bias[n]), batched via blockIdx.z
constexpr int EPI_F32 = 4;     // out: f32 acc+bias[n]

template <bool SPLIT, bool SELB, int EPI>
__global__ __launch_bounds__(256) void gemm_bt(
    const ushort* __restrict__ Ah, const ushort* __restrict__ Al,
    const ushort* __restrict__ Bh, const ushort* __restrict__ Bl,
    const uint32* __restrict__ bmask,
    int N, int K, long long a_bs, long long o_bs, long long bias_bs,
    const float* __restrict__ bias,
    void* __restrict__ outp, void* __restrict__ out2p,
    uint32* __restrict__ keys, int storek,
    uint32* __restrict__ hist, uint32* __restrict__ hmax,
    const uint32* __restrict__ meta) {
  static_assert((EPI != EPI_SCORE && EPI != EPI_REFINE) || SPLIT, "score paths are split");
  __shared__ __align__(16) ushort lds[SPLIT ? 16384 : 8192];
  ushort* As = lds;
  ushort* Bs = lds + (SPLIT ? 8192 : 4096);

  const int tid = threadIdx.x;
  const int w = tid >> 6, l = tid & 63;
  const int wm = (w >> 1) << 6, wn = (w & 1) << 6;
  const int lm = l & 15, lq = l >> 4;
  const int m0 = blockIdx.y << 7, n0 = blockIdx.x << 7;
  const int z = blockIdx.z;

  const ushort* pAh = Ah + (size_t)z * a_bs + (size_t)m0 * K;
  const ushort* pAl = SPLIT ? Al + (size_t)z * a_bs + (size_t)m0 * K : nullptr;
  const ushort* pBh = SELB ? nullptr : Bh + (size_t)n0 * K;
  const ushort* pBl = (SPLIT && !SELB) ? Bl + (size_t)n0 * K : nullptr;
  const uint32* bm = SELB ? bmask + (size_t)z * Hn : nullptr;

  floatx4 acc[4][4];
#pragma unroll
  for (int i = 0; i < 4; i++)
#pragma unroll
    for (int j = 0; j < 4; j++) acc[i][j] = floatx4{0.f, 0.f, 0.f, 0.f};

  for (int k0 = 0; k0 < K; k0 += 32) {
    stage_tile(As, pAh + k0, K, tid);
    if constexpr (SELB)
      stage_tile_sel(Bs, Bh, Bl, bm, n0, k0, K, tid);
    else
      stage_tile(Bs, pBh + k0, K, tid);
    if constexpr (SPLIT) {
      stage_tile(As + 4096, pAl + k0, K, tid);
      stage_tile(Bs + 4096, pBl + k0, K, tid);
    }
    __syncthreads();
    short8 afh[4], bfh[4];
#pragma unroll
    for (int i = 0; i < 4; i++)
      afh[i] = *(const short8*)&As[(wm + i * 16 + lm) * 32 + lq * 8];
#pragma unroll
    for (int i = 0; i < 4; i++)
      bfh[i] = *(const short8*)&Bs[(wn + i * 16 + lm) * 32 + lq * 8];
#pragma unroll
    for (int mi = 0; mi < 4; mi++)
#pragma unroll
      for (int ni = 0; ni < 4; ni++)
        acc[mi][ni] = __builtin_amdgcn_mfma_f32_16x16x32_bf16(afh[mi], bfh[ni], acc[mi][ni], 0, 0, 0);
    if constexpr (SPLIT) {
      short8 bfl[4];
#pragma unroll
      for (int i = 0; i < 4; i++)
        bfl[i] = *(const short8*)&Bs[4096 + (wn + i * 16 + lm) * 32 + lq * 8];
#pragma unroll
      for (int mi = 0; mi < 4; mi++)
#pragma unroll
        for (int ni = 0; ni < 4; ni++)
          acc[mi][ni] = __builtin_amdgcn_mfma_f32_16x16x32_bf16(afh[mi], bfl[ni], acc[mi][ni], 0, 0, 0);
      short8 afl[4];
#pragma unroll
      for (int i = 0; i < 4; i++)
        afl[i] = *(const short8*)&As[4096 + (wm + i * 16 + lm) * 32 + lq * 8];
#pragma unroll
      for (int mi = 0; mi < 4; mi++)
#pragma unroll
        for (int ni = 0; ni < 4; ni++)
          acc[mi][ni] = __builtin_amdgcn_mfma_f32_16x16x32_bf16(afl[mi], bfh[ni], acc[mi][ni], 0, 0, 0);
    }
    __syncthreads();
  }

  // ---- epilogue. D layout: row m = wm+mi*16+lq*4+r, col n = wn+ni*16+lm (m89/m91) ----
  if constexpr (EPI == EPI_RELU) {
    ushort* rh = (ushort*)outp;
    ushort* rl = (ushort*)out2p;
#pragma unroll
    for (int mi = 0; mi < 4; mi++)
#pragma unroll
      for (int ni = 0; ni < 4; ni++) {
        int gm = m0 + wm + mi * 16 + lq * 4;
        int gn = n0 + wn + ni * 16 + lm;
        float bnv = bias[gn];
#pragma unroll
        for (int r = 0; r < 4; r++) {
          float v = fmaxf(acc[mi][ni][r] + bnv, 0.f);
          ushort h = f2bf(v);
          size_t o = (size_t)(gm + r) * N + gn;
          rh[o] = h;
          rl[o] = f2bf(v - bf2f(h));
        }
      }
  } else if constexpr (EPI == EPI_SILU) {
    ushort* o = (ushort*)outp + (size_t)z * o_bs;
    const float* bb = bias + (size_t)z * bias_bs;
#pragma unroll
    for (int mi = 0; mi < 4; mi++)
#pragma unroll
      for (int ni = 0; ni < 4; ni++) {
        int gm = m0 + wm + mi * 16 + lq * 4;
        int gn = n0 + wn + ni * 16 + lm;
        float bnv = bb[gn];
#pragma unroll
        for (int r = 0; r < 4; r++) {
          float v = acc[mi][ni][r] + bnv;
          float s = v / (1.f + __expf(-v));
          o[(size_t)(gm + r) * N + gn] = f2bf(s);
        }
      }
  } else if constexpr (EPI == EPI_F32) {
    float* o = (float*)outp;
#pragma unroll
    for (int mi = 0; mi < 4; mi++)
#pragma unroll
      for (int ni = 0; ni < 4; ni++) {
        int gm = m0 + wm + mi * 16 + lq * 4;
        int gn = n0 + wn + ni * 16 + lm;
        float bnv = bias[gn];
#pragma unroll
        for (int r = 0; r < 4; r++)
          o[(size_t)(gm + r) * N + gn] = acc[mi][ni][r] + bnv;
      }
  } else if constexpr (EPI == EPI_SCORE) {
    // tiles are dead -> overlay 8192-bin u32 LDS histogram (32 KB)
    uint32* hs = (uint32*)lds;
    for (int i = tid; i < 8192; i += 256) hs[i] = 0;
    __syncthreads();
    const int batch = m0 >> 10;  // 128-row blocks never straddle a batch
#pragma unroll
    for (int ni = 0; ni < 4; ni++) {
      int gn = n0 + wn + ni * 16 + lm;
      float bnv = bias[gn];
      float vmax = -3.4e38f;
#pragma unroll
      for (int mi = 0; mi < 4; mi++) {
        int gm = m0 + wm + mi * 16 + lq * 4;
#pragma unroll
        for (int r = 0; r < 4; r++) {
          float v = acc[mi][ni][r] + bnv;
          uint32 e = ekey(skey(v));
          if (storek) keys[(size_t)(gm + r) * N + gn] = e;
          atomicAdd(&hs[e >> 14], 1u);
          vmax = fmaxf(vmax, v);
        }
      }
      atomicMax(&hmax[batch * Hn + gn], skey(vmax));  // all 16 values share column gn
    }
    __syncthreads();
    for (int i = tid; i < 8192; i += 256) {
      uint32 c = hs[i];
      if (c) atomicAdd(&hist[batch * 8192 + i], c);
    }
  } else {  // EPI_REFINE: bit-exact re-run; rare global atomics for boundary bucket only
    const int batch = m0 >> 10;
    const uint32 j = meta[8 + batch];
#pragma unroll
    for (int ni = 0; ni < 4; ni++) {
      int gn = n0 + wn + ni * 16 + lm;
      float bnv = bias[gn];
#pragma unroll
      for (int mi = 0; mi < 4; mi++) {
#pragma unroll
        for (int r = 0; r < 4; r++) {
          float v = acc[mi][ni][r] + bnv;
          uint32 e = ekey(skey(v));
          if ((e >> 14) == j) atomicAdd(&hist[batch * 16384 + (e & 0x3FFFu)], 1u);
        }
      }
    }
  }
}

// ---------------- selection kernels ----------------
// meta[0..7]=threshold key (skey space), meta[8..15]=bucket j, meta[16..23]=need-in-bucket
__global__ __launch_bounds__(256) void select1_k(const uint32* __restrict__ hist,
                                                 uint32* __restrict__ meta) {
  int b = blockIdx.x;
  const uint32* h = hist + b * 8192;
  __shared__ uint32 ps[256];
  uint32 s = 0;
  int base = threadIdx.x * 32;
  for (int i = 0; i < 32; i++) s += h[base + i];
  ps[threadIdx.x] = s;
  __syncthreads();
  if (threadIdx.x == 0) {
    uint32 cum = 0, need = 1;
    int j = 0;
    for (int c = 255; c >= 0; c--) {
      if (cum + ps[c] >= KTOP) {
        for (int i = c * 32 + 31;; i--) {
          uint32 hv = h[i];
          if (cum + hv >= KTOP) { j = i; need = KTOP - cum; break; }
          cum += hv;
        }
        break;
      }
      cum += ps[c];
    }
    meta[8 + b] = (uint32)j;
    meta[16 + b] = need;
    meta[b] = SKBASE + ((uint32)j << 14);  // provisional; select2 overwrites
  }
}

// LARGE path: filter stored compact keys into boundary-bucket remainder histogram
__global__ __launch_bounds__(256) void refine_k(const uint32* __restrict__ keys,
                                                const uint32* __restrict__ meta,
                                                uint32* __restrict__ hist2) {
  size_t stride = (size_t)gridDim.x * 256;
  for (size_t i = (size_t)blockIdx.x * 256 + threadIdx.x; i < NRS; i += stride) {
    int b = (int)(i >> 22);  // S*H = 2^22 per batch
    uint32 e = keys[i];
    if ((e >> 14) == meta[8 + b]) atomicAdd(&hist2[(size_t)b * 16384 + (e & 0x3FFFu)], 1u);
  }
}

__global__ __launch_bounds__(256) void select2_k(const uint32* __restrict__ hist2,
                                                 uint32* __restrict__ meta) {
  int b = blockIdx.x;
  const uint32* h2 = hist2 + (size_t)b * 16384;
  __shared__ uint32 ps[256];
  uint32 s = 0;
  const uint32* p = h2 + (size_t)threadIdx.x * 64;
  for (int i = 0; i < 64; i += 4) {
    uint4 v = *(const uint4*)(p + i);
    s += v.x + v.y + v.z + v.w;
  }
  ps[threadIdx.x] = s;
  __syncthreads();
  if (threadIdx.x == 0) {
    uint32 need = meta[16 + b];
    uint32 j = meta[8 + b];
    uint32 cum = 0;
    int c = 255;
    for (; c > 0; c--) {
      if (cum + ps[c] >= need) break;
      cum += ps[c];
    }
    uint32 rem = 0;
    for (int i = 63; i >= 0; i--) {
      uint32 hv = h2[c * 64 + i];
      if (cum + hv >= need) { rem = (uint32)(c * 64 + i); break; }
      cum += hv;
    }
    meta[b] = SKBASE + (j << 14) + rem;  // exact 32-bit threshold
  }
}

__global__ __launch_bounds__(256) void mask_k(const uint32* __restrict__ hmax,
                                              const uint32* __restrict__ meta,
                                              const float* __restrict__ modb,
                                              const float* __restrict__ upb,
                                              uint32* __restrict__ mask,
                                              float* __restrict__ bsel) {
  int i = blockIdx.x * 256 + threadIdx.x;  // Bn*Hn = 32768
  int b = i >> 12, h = i & 4095;
  bool m = hmax[i] >= meta[b];
  mask[i] = m ? 1u : 0u;
  bsel[i] = m ? modb[h] : upb[h];
}

// ---------------- launch ----------------
extern "C" void kernel_launch(void* const* d_in, const int* in_sizes, int n_in,
                              void* d_out, int out_size, void* d_ws, size_t ws_size,
                              hipStream_t stream) {
  (void)in_sizes; (void)n_in;
  const float* x    = (const float*)d_in[0];
  const float* up_w = (const float*)d_in[1];
  const float* up_b = (const float*)d_in[2];
  const float* g_w1 = (const float*)d_in[3];
  const float* g_b1 = (const float*)d_in[4];
  const float* g_w2 = (const float*)d_in[5];
  const float* g_b2 = (const float*)d_in[6];
  const float* mod_w= (const float*)d_in[7];
  const float* mod_b= (const float*)d_in[8];
  const float* dw   = (const float*)d_in[9];
  const float* db   = (const float*)d_in[10];
  float* out = (float*)d_out;

  // plan: 2 = keys stored (1 G2 pass + cheap refine), 1 = G2 re-run for refine,
  //       0 = workspace too small -> emit zeros (clean diagnosable absmax failure)
  const int plan = ws_size >= WS_LARGE ? 2 : (ws_size >= WS_SMALL ? 1 : 0);
  if (plan == 0) {
    zero_out_k<<<(out_size + 255) / 256, 256, 0, stream>>>(out, out_size);
    return;
  }

  char* ws = (char*)d_ws;
  ushort* XH  = (ushort*)(ws + OFF_XH);
  ushort* XL  = (ushort*)(ws + OFF_XL);
  ushort* W1H = (ushort*)(ws + OFF_W1H);
  ushort* W1L = (ushort*)(ws + OFF_W1L);
  ushort* W2H = (ushort*)(ws + OFF_W2H);
  ushort* W2L = (ushort*)(ws + OFF_W2L);
  ushort* RSH = (ushort*)(ws + OFF_RSH);
  ushort* RSL = (ushort*)(ws + OFF_RSL);
  uint32* HIST = (uint32*)(ws + OFF_HIST);
  uint32* HIST2= (uint32*)(ws + OFF_HIST2);
  uint32* HMAX = (uint32*)(ws + OFF_HMAX);
  float*  BSEL = (float*)(ws + OFF_BSEL);
  uint32* MASK = (uint32*)(ws + OFF_MASK);
  uint32* META = (uint32*)(ws + OFF_META);
  uint32* KEYS = (uint32*)(ws + OFF_KEYS);
  ushort* UPW  = W1H;   // reuse: W1 dead after G1
  ushort* MODW = W1L;
  ushort* DWNW = XL;    // reuse: XL dead after G1 (8 of 16 MB)
  ushort* HBUF = RSH;   // reuse: RSH dead after G2/G2b

  hipMemsetAsync(ws + OFF_HIST, 0, ZERO_BYTES, stream);

  cvt_split_k<<<1024, 256, 0, stream>>>((const float4*)x, XH, XL, (int)(NX / 4));
  cvt_split_k<<<1024, 256, 0, stream>>>((const float4*)g_w1, W1H, W1L, (int)(NW1 / 4));
  cvt_split_k<<<2048, 256, 0, stream>>>((const float4*)g_w2, W2H, W2L, (int)(NW2 / 4));

  // G1: rs = relu(X*W1^T + b1), split-bf16, split store
  gemm_bt<true, false, EPI_RELU><<<dim3(Hn / 128, (Bn * Sn) / 128, 1), 256, 0, stream>>>(
      XH, XL, W1H, W1L, nullptr, Hn, Dn, 0, 0, 0, g_b1, RSH, RSL,
      nullptr, 0, nullptr, nullptr, nullptr);
  // G2: scores = rs*W2^T + b2; fused hist/colmax (+keys if plan 2)
  gemm_bt<true, false, EPI_SCORE><<<dim3(Hn / 128, (Bn * Sn) / 128, 1), 256, 0, stream>>>(
      RSH, RSL, W2H, W2L, nullptr, Hn, Hn, 0, 0, 0, g_b2, nullptr, nullptr,
      KEYS, plan == 2 ? 1 : 0, HIST, HMAX, nullptr);
  select1_k<<<Bn, 256, 0, stream>>>(HIST, META);
  if (plan == 2) {
    refine_k<<<8192, 256, 0, stream>>>(KEYS, META, HIST2);
  } else {
    // bit-exact score re-run; only boundary-bucket elements touch hist2
    gemm_bt<true, false, EPI_REFINE><<<dim3(Hn / 128, (Bn * Sn) / 128, 1), 256, 0, stream>>>(
        RSH, RSL, W2H, W2L, nullptr, Hn, Hn, 0, 0, 0, g_b2, nullptr, nullptr,
        nullptr, 0, HIST2, nullptr, META);
  }
  select2_k<<<Bn, 256, 0, stream>>>(HIST2, META);
  mask_k<<<(Bn * Hn) / 256, 256, 0, stream>>>(HMAX, META, mod_b, up_b, MASK, BSEL);

  // lazy conversions into regions dead after G1
  cvt_single_k<<<1024, 256, 0, stream>>>((const float4*)up_w, UPW, (int)(NW1 / 4));
  cvt_single_k<<<1024, 256, 0, stream>>>((const float4*)mod_w, MODW, (int)(NW1 / 4));
  cvt_single_k<<<1024, 256, 0, stream>>>((const float4*)dw, DWNW, (int)(NW1 / 4));

  // G3: h = silu(X * sel_w^T + sel_b), B rows selected per-lane at staging time
  gemm_bt<false, true, EPI_SILU><<<dim3(Hn / 128, Sn / 128, Bn), 256, 0, stream>>>(
      XH, nullptr, UPW, MODW, MASK, Hn, Dn,
      (long long)Sn * Dn, (long long)Sn * Hn, (long long)Hn,
      BSEL, HBUF, nullptr, nullptr, 0, nullptr, nullptr, nullptr);
  // G4: out = h * down_w^T + down_b (fp32 out)
  gemm_bt<false, false, EPI_F32><<<dim3(Dn / 128, (Bn * Sn) / 128, 1), 256, 0, stream>>>(
      HBUF, nullptr, DWNW, nullptr, nullptr, Dn, Hn, 0, 0, 0, db, out, nullptr,
      nullptr, 0, nullptr, nullptr, nullptr);
}

// Round 3
// 1579.972 us; speedup vs baseline: 1.4527x; 1.4527x over previous
//
#include <hip/hip_runtime.h>
#include <cstdint>

typedef __attribute__((ext_vector_type(8))) short short8;
typedef __attribute__((ext_vector_type(4))) float floatx4;
typedef unsigned int uint32;

typedef const void __attribute__((address_space(1)))* gcptr;
typedef void __attribute__((address_space(3)))* lptr;

// ---------------- problem dims ----------------
constexpr int Bn = 8, Sn = 1024, Dn = 1024, Hn = 4096;
constexpr uint32 KTOP = 1024u * 1024u;   // min(TOP_K*S, S*H) = 2^20
// 27-bit compact key space: e = clamp(skey(v) - SKBASE, 0, 2^27-1)
// covers score values in (2^-9, 128); bin = e>>14 (8192 bins), rem = e&0x3FFF
constexpr uint32 SKBASE = 0xBB000000u;   // skey of +2^-9
constexpr uint32 EMAX = (1u << 27) - 1u;
// threshold window: scores in [0.28, 0.56] are candidates for the k-th largest
// (t ~= 0.39 analytically; window covers +-40% model error; guarded fallback if missed)
constexpr uint32 WLO = 3645;             // bucket of 0.28
constexpr uint32 WHI = 4157;             // bucket of 0.56
constexpr uint32 CAP = 1u << 20;         // per-batch buffer capacity (8*CAP*4 = 32 MiB)

// ---------------- workspace layout (bytes) ----------------
constexpr size_t NX  = (size_t)Bn * Sn * Dn;   // 8388608
constexpr size_t NW1 = (size_t)Hn * Dn;        // 4194304
constexpr size_t NW2 = (size_t)Hn * Hn;        // 16777216
constexpr size_t NRS = (size_t)Bn * Sn * Hn;   // 33554432

constexpr size_t OFF_XH   = 0;                         // 16 MB (live: G1,G3)
constexpr size_t OFF_XL   = OFF_XH  + 2 * NX;          // 16 MB (G1; then BUF, then DWNW)
constexpr size_t OFF_W1H  = OFF_XL  + 2 * NX;          // 8 MB  (G1; then BUF, then UPW)
constexpr size_t OFF_W1L  = OFF_W1H + 2 * NW1;         // 8 MB  (G1; then BUF, then MODW)
constexpr size_t OFF_W2H  = OFF_W1L + 2 * NW1;         // 32 MB (G2)
constexpr size_t OFF_W2L  = OFF_W2H + 2 * NW2;         // 32 MB (G2)
constexpr size_t OFF_RSH  = OFF_W2L + 2 * NW2;         // 64 MB (G1->G2; then HBUF)
constexpr size_t OFF_RSL  = OFF_RSH + 2 * NRS;         // 64 MB (G1->G2)
constexpr size_t OFF_HIST = OFF_RSL + 2 * NRS;         // 8 x 8192 u32  (zeroed)
constexpr size_t OFF_HIST2= OFF_HIST + (size_t)Bn * 8192 * 4;   // 8 x 16384 u32 (zeroed)
constexpr size_t OFF_HMAX = OFF_HIST2+ (size_t)Bn * 16384 * 4;  // 8 x 4096 u32  (zeroed)
constexpr size_t OFF_META = OFF_HMAX + (size_t)Bn * Hn * 4;     // 1024 u32      (zeroed)
constexpr size_t OFF_BSEL = OFF_META + 4096;           // 8 x 4096 f32
constexpr size_t OFF_MASK = OFF_BSEL + (size_t)Bn * Hn * 4;     // 8 x 4096 u32
constexpr size_t WS_SMALL = OFF_MASK + (size_t)Bn * Hn * 4;     // ~241.2 MB
constexpr size_t ZERO_BYTES = OFF_BSEL - OFF_HIST;     // hist + hist2 + hmax + meta
// BUF lives in the dead XL/W1H/W1L span (exactly 32 MiB) during G2..refine
constexpr size_t OFF_BUF  = OFF_XL;

// ---------------- helpers ----------------
__device__ __forceinline__ ushort f2bf(float f) {        // fp32 -> bf16 RNE
  uint32 u = __float_as_uint(f);
  u += 0x7fffu + ((u >> 16) & 1u);
  return (ushort)(u >> 16);
}
__device__ __forceinline__ float bf2f(ushort h) {
  return __uint_as_float(((uint32)h) << 16);
}
__device__ __forceinline__ uint32 skey(float v) {        // monotone fp32 -> u32 key
  uint32 u = __float_as_uint(v);
  return (u & 0x80000000u) ? ~u : (u | 0x80000000u);
}
__device__ __forceinline__ uint32 ekey(uint32 key) {     // 27-bit compact key
  if (key <= SKBASE) return 0u;
  uint32 d = key - SKBASE;
  return d > EMAX ? EMAX : d;
}
__device__ __forceinline__ void g2l(const ushort* src, ushort* dst) {
  __builtin_amdgcn_global_load_lds((gcptr)src, (lptr)dst, 16, 0, 0);
}
// stage one 128x32 bf16 tile (8 KB) via global_load_lds width=16.
// LDS dest is wave-uniform base + lane*16 (m104/m108 rule) -> unpadded row-major layout.
__device__ __forceinline__ void stage_tile(ushort* lds, const ushort* gbase, int ldg, int tid) {
  const int w = tid >> 6;
  const int c0 = tid, c1 = tid + 256;
  g2l(gbase + (size_t)(c0 >> 2) * ldg + (c0 & 3) * 8, lds + (size_t)(w * 64) * 8);
  g2l(gbase + (size_t)(c1 >> 2) * ldg + (c1 & 3) * 8, lds + (size_t)(256 + w * 64) * 8);
}
// same, but per-row source select between mod_w / up_w via mask (per-lane global address ok)
__device__ __forceinline__ void stage_tile_sel(ushort* lds, const ushort* upw,
                                               const ushort* modw, const uint32* bm,
                                               int n0, int k0, int ldg, int tid) {
  const int w = tid >> 6;
  const int c0 = tid, c1 = tid + 256;
  const int r0 = n0 + (c0 >> 2), r1 = n0 + (c1 >> 2);
  const ushort* s0 = (bm[r0] ? modw : upw) + (size_t)r0 * ldg + k0 + (c0 & 3) * 8;
  const ushort* s1 = (bm[r1] ? modw : upw) + (size_t)r1 * ldg + k0 + (c1 & 3) * 8;
  g2l(s0, lds + (size_t)(w * 64) * 8);
  g2l(s1, lds + (size_t)(256 + w * 64) * 8);
}

// ---------------- conversion kernels ----------------
__global__ __launch_bounds__(256) void cvt_split_k(const float4* __restrict__ x,
                                                   ushort* __restrict__ hi,
                                                   ushort* __restrict__ lo, int n4) {
  int stride = gridDim.x * 256;
  for (int i = blockIdx.x * 256 + threadIdx.x; i < n4; i += stride) {
    float4 v = x[i];
    ushort h0 = f2bf(v.x), h1 = f2bf(v.y), h2 = f2bf(v.z), h3 = f2bf(v.w);
    ushort4 hv; hv.x = h0; hv.y = h1; hv.z = h2; hv.w = h3;
    *(ushort4*)(hi + (size_t)i * 4) = hv;
    ushort4 lv;
    lv.x = f2bf(v.x - bf2f(h0)); lv.y = f2bf(v.y - bf2f(h1));
    lv.z = f2bf(v.z - bf2f(h2)); lv.w = f2bf(v.w - bf2f(h3));
    *(ushort4*)(lo + (size_t)i * 4) = lv;
  }
}
__global__ __launch_bounds__(256) void cvt_single_k(const float4* __restrict__ x,
                                                    ushort* __restrict__ hi, int n4) {
  int stride = gridDim.x * 256;
  for (int i = blockIdx.x * 256 + threadIdx.x; i < n4; i += stride) {
    float4 v = x[i];
    ushort4 hv; hv.x = f2bf(v.x); hv.y = f2bf(v.y); hv.z = f2bf(v.z); hv.w = f2bf(v.w);
    *(ushort4*)(hi + (size_t)i * 4) = hv;
  }
}
__global__ __launch_bounds__(256) void zero_out_k(float* __restrict__ o, int n) {
  int i = blockIdx.x * 256 + threadIdx.x;
  if (i < n) o[i] = 0.f;
}

// ---------------- GEMM: C[m,n] = sum_k A[m,k]*B[n,k] (+epilogue) ----------------
// 128x128 tile, BK=32, 4 waves (2x2 of 64x64), mfma_f32_16x16x32_bf16.
// SPLIT: A,B given as hi+lo bf16 pairs; acc += Ah*Bh + Ah*Bl + Al*Bh (near-fp32 product).
// SELB:  B rows staged per-row from (mask ? modw : upw).
constexpr int EPI_RELU = 0;    // out: rs_hi/rs_lo bf16 split of relu(acc+bias[n])
constexpr int EPI_SCORE = 1;   // hist/colmax + windowed key append of acc+bias[n]
constexpr int EPI_SILU = 2;    // out: bf16 silu(acc+bias[n]), batched via blockIdx.z
constexpr int EPI_F32 = 3;     // out: f32 acc+bias[n]

template <bool SPLIT, bool SELB, int EPI>
__global__ __launch_bounds__(256) void gemm_bt(
    const ushort* __restrict__ Ah, const ushort* __restrict__ Al,
    const ushort* __restrict__ Bh, const ushort* __restrict__ Bl,
    const uint32* __restrict__ bmask,
    int N, int K, long long a_bs, long long o_bs, long long bias_bs,
    const float* __restrict__ bias,
    void* __restrict__ outp, void* __restrict__ out2p,
    uint32* __restrict__ hist, uint32* __restrict__ hmax,
    uint32* __restrict__ buf, uint32* __restrict__ cnt) {
  static_assert(EPI != EPI_SCORE || SPLIT, "score path is split");
  __shared__ __align__(16) ushort lds[SPLIT ? 16384 : 8192];
  ushort* As = lds;
  ushort* Bs = lds + (SPLIT ? 8192 : 4096);

  const int tid = threadIdx.x;
  const int w = tid >> 6, l = tid & 63;
  const int wm = (w >> 1) << 6, wn = (w & 1) << 6;
  const int lm = l & 15, lq = l >> 4;
  const int m0 = blockIdx.y << 7, n0 = blockIdx.x << 7;
  const int z = blockIdx.z;

  const ushort* pAh = Ah + (size_t)z * a_bs + (size_t)m0 * K;
  const ushort* pAl = SPLIT ? Al + (size_t)z * a_bs + (size_t)m0 * K : nullptr;
  const ushort* pBh = SELB ? nullptr : Bh + (size_t)n0 * K;
  const ushort* pBl = (SPLIT && !SELB) ? Bl + (size_t)n0 * K : nullptr;
  const uint32* bm = SELB ? bmask + (size_t)z * Hn : nullptr;

  floatx4 acc[4][4];
#pragma unroll
  for (int i = 0; i < 4; i++)
#pragma unroll
    for (int j = 0; j < 4; j++) acc[i][j] = floatx4{0.f, 0.f, 0.f, 0.f};

  for (int k0 = 0; k0 < K; k0 += 32) {
    stage_tile(As, pAh + k0, K, tid);
    if constexpr (SELB)
      stage_tile_sel(Bs, Bh, Bl, bm, n0, k0, K, tid);
    else
      stage_tile(Bs, pBh + k0, K, tid);
    if constexpr (SPLIT) {
      stage_tile(As + 4096, pAl + k0, K, tid);
      stage_tile(Bs + 4096, pBl + k0, K, tid);
    }
    __syncthreads();
    short8 afh[4], bfh[4];
#pragma unroll
    for (int i = 0; i < 4; i++)
      afh[i] = *(const short8*)&As[(wm + i * 16 + lm) * 32 + lq * 8];
#pragma unroll
    for (int i = 0; i < 4; i++)
      bfh[i] = *(const short8*)&Bs[(wn + i * 16 + lm) * 32 + lq * 8];
#pragma unroll
    for (int mi = 0; mi < 4; mi++)
#pragma unroll
      for (int ni = 0; ni < 4; ni++)
        acc[mi][ni] = __builtin_amdgcn_mfma_f32_16x16x32_bf16(afh[mi], bfh[ni], acc[mi][ni], 0, 0, 0);
    if constexpr (SPLIT) {
      short8 bfl[4];
#pragma unroll
      for (int i = 0; i < 4; i++)
        bfl[i] = *(const short8*)&Bs[4096 + (wn + i * 16 + lm) * 32 + lq * 8];
#pragma unroll
      for (int mi = 0; mi < 4; mi++)
#pragma unroll
        for (int ni = 0; ni < 4; ni++)
          acc[mi][ni] = __builtin_amdgcn_mfma_f32_16x16x32_bf16(afh[mi], bfl[ni], acc[mi][ni], 0, 0, 0);
      short8 afl[4];
#pragma unroll
      for (int i = 0; i < 4; i++)
        afl[i] = *(const short8*)&As[4096 + (wm + i * 16 + lm) * 32 + lq * 8];
#pragma unroll
      for (int mi = 0; mi < 4; mi++)
#pragma unroll
        for (int ni = 0; ni < 4; ni++)
          acc[mi][ni] = __builtin_amdgcn_mfma_f32_16x16x32_bf16(afl[mi], bfh[ni], acc[mi][ni], 0, 0, 0);
    }
    __syncthreads();
  }

  // ---- epilogue. D layout: row m = wm+mi*16+lq*4+r, col n = wn+ni*16+lm (m89/m91) ----
  if constexpr (EPI == EPI_RELU) {
    ushort* rh = (ushort*)outp;
    ushort* rl = (ushort*)out2p;
#pragma unroll
    for (int mi = 0; mi < 4; mi++)
#pragma unroll
      for (int ni = 0; ni < 4; ni++) {
        int gm = m0 + wm + mi * 16 + lq * 4;
        int gn = n0 + wn + ni * 16 + lm;
        float bnv = bias[gn];
#pragma unroll
        for (int r = 0; r < 4; r++) {
          float v = fmaxf(acc[mi][ni][r] + bnv, 0.f);
          ushort h = f2bf(v);
          size_t o = (size_t)(gm + r) * N + gn;
          rh[o] = h;
          rl[o] = f2bf(v - bf2f(h));
        }
      }
  } else if constexpr (EPI == EPI_SILU) {
    ushort* o = (ushort*)outp + (size_t)z * o_bs;
    const float* bb = bias + (size_t)z * bias_bs;
#pragma unroll
    for (int mi = 0; mi < 4; mi++)
#pragma unroll
      for (int ni = 0; ni < 4; ni++) {
        int gm = m0 + wm + mi * 16 + lq * 4;
        int gn = n0 + wn + ni * 16 + lm;
        float bnv = bb[gn];
#pragma unroll
        for (int r = 0; r < 4; r++) {
          float v = acc[mi][ni][r] + bnv;
          float s = v / (1.f + __expf(-v));
          o[(size_t)(gm + r) * N + gn] = f2bf(s);
        }
      }
  } else if constexpr (EPI == EPI_F32) {
    float* o = (float*)outp;
#pragma unroll
    for (int mi = 0; mi < 4; mi++)
#pragma unroll
      for (int ni = 0; ni < 4; ni++) {
        int gm = m0 + wm + mi * 16 + lq * 4;
        int gn = n0 + wn + ni * 16 + lm;
        float bnv = bias[gn];
#pragma unroll
        for (int r = 0; r < 4; r++)
          o[(size_t)(gm + r) * N + gn] = acc[mi][ni][r] + bnv;
      }
  } else {  // EPI_SCORE: tiles dead -> overlay 8192-bin u32 LDS histogram (32 KB)
    uint32* hs = (uint32*)lds;
    for (int i = tid; i < 8192; i += 256) hs[i] = 0;
    __syncthreads();
    const int batch = m0 >> 10;  // 128-row blocks never straddle a batch
    uint32 cntl = 0;             // lane's in-window count
#pragma unroll
    for (int ni = 0; ni < 4; ni++) {
      int gn = n0 + wn + ni * 16 + lm;
      float bnv = bias[gn];
      float vmax = -3.4e38f;
#pragma unroll
      for (int mi = 0; mi < 4; mi++) {
#pragma unroll
        for (int r = 0; r < 4; r++) {
          float v = acc[mi][ni][r] + bnv;
          uint32 e = ekey(skey(v));
          uint32 bk = e >> 14;
          atomicAdd(&hs[bk], 1u);
          if (bk >= WLO && bk <= WHI) cntl++;
          vmax = fmaxf(vmax, v);
        }
      }
      atomicMax(&hmax[batch * Hn + gn], skey(vmax));  // all 16 values share column gn
    }
    __syncthreads();
    for (int i = tid; i < 8192; i += 256) {
      uint32 c = hs[i];
      if (c) atomicAdd(&hist[batch * 8192 + i], c);
    }
    __syncthreads();
    // block-aggregated append of in-window keys: one global atomic per block
    hs[tid] = cntl;
    __syncthreads();
    if (tid == 0) {
      uint32 run = 0;
      for (int i = 0; i < 256; i++) { uint32 t = hs[i]; hs[i] = run; run += t; }
      hs[256] = atomicAdd(&cnt[batch], run);
    }
    __syncthreads();
    uint32 off = hs[256] + hs[tid];
    uint32* bb = buf + (size_t)batch * CAP;
#pragma unroll
    for (int ni = 0; ni < 4; ni++) {
      int gn = n0 + wn + ni * 16 + lm;
      float bnv = bias[gn];
#pragma unroll
      for (int mi = 0; mi < 4; mi++) {
#pragma unroll
        for (int r = 0; r < 4; r++) {
          float v = acc[mi][ni][r] + bnv;
          uint32 e = ekey(skey(v));
          uint32 bk = e >> 14;
          if (bk >= WLO && bk <= WHI) {
            if (off < CAP) bb[off] = e;
            off++;
          }
        }
      }
    }
  }
}

// ---------------- selection kernels ----------------
// meta[0..7]=threshold key (skey space), meta[8..15]=bucket j, meta[16..23]=need-in-bucket,
// meta[32..39]=per-batch append counters (zeroed with the hist block)
__global__ __launch_bounds__(256) void select1_k(const uint32* __restrict__ hist,
                                                 uint32* __restrict__ meta) {
  int b = blockIdx.x;
  const uint32* h = hist + b * 8192;
  __shared__ uint32 ps[256];
  uint32 s = 0;
  int base = threadIdx.x * 32;
  for (int i = 0; i < 32; i++) s += h[base + i];
  ps[threadIdx.x] = s;
  __syncthreads();
  if (threadIdx.x == 0) {
    uint32 cum = 0, need = 1;
    int j = 0;
    for (int c = 255; c >= 0; c--) {
      if (cum + ps[c] >= KTOP) {
        for (int i = c * 32 + 31;; i--) {
          uint32 hv = h[i];
          if (cum + hv >= KTOP) { j = i; need = KTOP - cum; break; }
          cum += hv;
        }
        break;
      }
      cum += ps[c];
    }
    meta[8 + b] = (uint32)j;
    meta[16 + b] = need;
    meta[b] = SKBASE + ((uint32)j << 14);  // bucket-edge fallback; select2 refines
  }
}

// build boundary-bucket remainder histogram from the windowed append buffer
__global__ __launch_bounds__(256) void refine_buf_k(const uint32* __restrict__ buf,
                                                    const uint32* __restrict__ meta,
                                                    uint32* __restrict__ hist2) {
  const uint32* cnt = meta + 32;
  size_t stride = (size_t)gridDim.x * 256;
  for (int b = 0; b < Bn; b++) {
    uint32 n = cnt[b] < CAP ? cnt[b] : CAP;
    uint32 j = meta[8 + b];
    const uint32* bb = buf + (size_t)b * CAP;
    for (size_t i = (size_t)blockIdx.x * 256 + threadIdx.x; i < n; i += stride) {
      uint32 e = bb[i];
      if ((e >> 14) == j) atomicAdd(&hist2[(size_t)b * 16384 + (e & 0x3FFFu)], 1u);
    }
  }
}

__global__ __launch_bounds__(256) void select2_k(const uint32* __restrict__ hist2,
                                                 uint32* __restrict__ meta) {
  int b = blockIdx.x;
  const uint32* h2 = hist2 + (size_t)b * 16384;
  __shared__ uint32 ps[256];
  uint32 s = 0;
  const uint32* p = h2 + (size_t)threadIdx.x * 64;
  for (int i = 0; i < 64; i += 4) {
    uint4 v = *(const uint4*)(p + i);
    s += v.x + v.y + v.z + v.w;
  }
  ps[threadIdx.x] = s;
  __syncthreads();
  if (threadIdx.x == 0) {
    uint32 j = meta[8 + b];
    uint32 valid = (j >= WLO && j <= WHI && meta[32 + b] <= CAP) ? 1u : 0u;
    if (valid) {
      uint32 need = meta[16 + b];
      uint32 cum = 0;
      int c = 255;
      for (; c > 0; c--) {
        if (cum + ps[c] >= need) break;
        cum += ps[c];
      }
      uint32 rem = 0;
      for (int i = 63; i >= 0; i--) {
        uint32 hv = h2[c * 64 + i];
        if (cum + hv >= need) { rem = (uint32)(c * 64 + i); break; }
        cum += hv;
      }
      meta[b] = SKBASE + (j << 14) + rem;  // exact 32-bit threshold
    }
    // else: keep select1's bucket-edge fallback
  }
}

__global__ __launch_bounds__(256) void mask_k(const uint32* __restrict__ hmax,
                                              const uint32* __restrict__ meta,
                                              const float* __restrict__ modb,
                                              const float* __restrict__ upb,
                                              uint32* __restrict__ mask,
                                              float* __restrict__ bsel) {
  int i = blockIdx.x * 256 + threadIdx.x;  // Bn*Hn = 32768
  int b = i >> 12, h = i & 4095;
  bool m = hmax[i] >= meta[b];
  mask[i] = m ? 1u : 0u;
  bsel[i] = m ? modb[h] : upb[h];
}

// ---------------- launch ----------------
extern "C" void kernel_launch(void* const* d_in, const int* in_sizes, int n_in,
                              void* d_out, int out_size, void* d_ws, size_t ws_size,
                              hipStream_t stream) {
  (void)in_sizes; (void)n_in;
  const float* x    = (const float*)d_in[0];
  const float* up_w = (const float*)d_in[1];
  const float* up_b = (const float*)d_in[2];
  const float* g_w1 = (const float*)d_in[3];
  const float* g_b1 = (const float*)d_in[4];
  const float* g_w2 = (const float*)d_in[5];
  const float* g_b2 = (const float*)d_in[6];
  const float* mod_w= (const float*)d_in[7];
  const float* mod_b= (const float*)d_in[8];
  const float* dw   = (const float*)d_in[9];
  const float* db   = (const float*)d_in[10];
  float* out = (float*)d_out;

  if (ws_size < WS_SMALL) {  // diagnosable clean failure instead of OOB fault
    zero_out_k<<<(out_size + 255) / 256, 256, 0, stream>>>(out, out_size);
    return;
  }

  char* ws = (char*)d_ws;
  ushort* XH  = (ushort*)(ws + OFF_XH);
  ushort* XL  = (ushort*)(ws + OFF_XL);
  ushort* W1H = (ushort*)(ws + OFF_W1H);
  ushort* W1L = (ushort*)(ws + OFF_W1L);
  ushort* W2H = (ushort*)(ws + OFF_W2H);
  ushort* W2L = (ushort*)(ws + OFF_W2L);
  ushort* RSH = (ushort*)(ws + OFF_RSH);
  ushort* RSL = (ushort*)(ws + OFF_RSL);
  uint32* HIST = (uint32*)(ws + OFF_HIST);
  uint32* HIST2= (uint32*)(ws + OFF_HIST2);
  uint32* HMAX = (uint32*)(ws + OFF_HMAX);
  uint32* META = (uint32*)(ws + OFF_META);
  float*  BSEL = (float*)(ws + OFF_BSEL);
  uint32* MASK = (uint32*)(ws + OFF_MASK);
  uint32* BUF  = (uint32*)(ws + OFF_BUF);
  ushort* UPW  = W1H;   // reuse: W1/BUF dead after refine
  ushort* MODW = W1L;
  ushort* DWNW = XL;
  ushort* HBUF = RSH;   // reuse: RSH dead after G2

  hipMemsetAsync(ws + OFF_HIST, 0, ZERO_BYTES, stream);

  cvt_split_k<<<1024, 256, 0, stream>>>((const float4*)x, XH, XL, (int)(NX / 4));
  cvt_split_k<<<1024, 256, 0, stream>>>((const float4*)g_w1, W1H, W1L, (int)(NW1 / 4));
  cvt_split_k<<<2048, 256, 0, stream>>>((const float4*)g_w2, W2H, W2L, (int)(NW2 / 4));

  // G1: rs = relu(X*W1^T + b1), split-bf16, split store
  gemm_bt<true, false, EPI_RELU><<<dim3(Hn / 128, (Bn * Sn) / 128, 1), 256, 0, stream>>>(
      XH, XL, W1H, W1L, nullptr, Hn, Dn, 0, 0, 0, g_b1, RSH, RSL,
      nullptr, nullptr, nullptr, nullptr);
  // G2: scores = rs*W2^T + b2; fused hist/colmax + windowed key append (BUF overlays XL/W1)
  gemm_bt<true, false, EPI_SCORE><<<dim3(Hn / 128, (Bn * Sn) / 128, 1), 256, 0, stream>>>(
      RSH, RSL, W2H, W2L, nullptr, Hn, Hn, 0, 0, 0, g_b2, nullptr, nullptr,
      HIST, HMAX, BUF, META + 32);
  select1_k<<<Bn, 256, 0, stream>>>(HIST, META);
  refine_buf_k<<<512, 256, 0, stream>>>(BUF, META, HIST2);
  select2_k<<<Bn, 256, 0, stream>>>(HIST2, META);
  mask_k<<<(Bn * Hn) / 256, 256, 0, stream>>>(HMAX, META, mod_b, up_b, MASK, BSEL);

  // lazy conversions into regions dead after refine (overwrite BUF)
  cvt_single_k<<<1024, 256, 0, stream>>>((const float4*)up_w, UPW, (int)(NW1 / 4));
  cvt_single_k<<<1024, 256, 0, stream>>>((const float4*)mod_w, MODW, (int)(NW1 / 4));
  cvt_single_k<<<1024, 256, 0, stream>>>((const float4*)dw, DWNW, (int)(NW1 / 4));

  // G3: h = silu(X * sel_w^T + sel_b), B rows selected per-lane at staging time
  gemm_bt<false, true, EPI_SILU><<<dim3(Hn / 128, Sn / 128, Bn), 256, 0, stream>>>(
      XH, nullptr, UPW, MODW, MASK, Hn, Dn,
      (long long)Sn * Dn, (long long)Sn * Hn, (long long)Hn,
      BSEL, HBUF, nullptr, nullptr, nullptr, nullptr, nullptr);
  // G4: out = h * down_w^T + down_b (fp32 out)
  gemm_bt<false, false, EPI_F32><<<dim3(Dn / 128, (Bn * Sn) / 128, 1), 256, 0, stream>>>(
      HBUF, nullptr, DWNW, nullptr, nullptr, Dn, Hn, 0, 0, 0, db, out, nullptr,
      nullptr, nullptr, nullptr, nullptr);
}

// Round 4
// 1560.606 us; speedup vs baseline: 1.4707x; 1.0124x over previous
//
#include <hip/hip_runtime.h>
#include <cstdint>

typedef __attribute__((ext_vector_type(8))) short short8;
typedef __attribute__((ext_vector_type(4))) float floatx4;
typedef unsigned int uint32;

typedef const void __attribute__((address_space(1)))* gcptr;
typedef void __attribute__((address_space(3)))* lptr;

// ---------------- problem dims ----------------
constexpr int Bn = 8, Sn = 1024, Dn = 1024, Hn = 4096;
constexpr uint32 KTOP = 1024u * 1024u;   // min(TOP_K*S, S*H) = 2^20
// 27-bit compact key space: e = clamp(skey(v) - SKBASE, 0, 2^27-1)
// covers score values in (2^-9, 128); bin = e>>14 (8192 bins), rem = e&0x3FFF
constexpr uint32 SKBASE = 0xBB000000u;   // skey of +2^-9
constexpr uint32 EMAX = (1u << 27) - 1u;
// threshold window: scores in [0.28, 0.56] are candidates for the k-th largest
// (t ~= 0.39 analytically; window covers +-40% model error; guarded fallback if missed)
constexpr uint32 WLO = 3645;             // bucket of 0.28
constexpr uint32 WHI = 4157;             // bucket of 0.56
constexpr uint32 CAP = 1u << 20;         // per-batch buffer capacity (8*CAP*4 = 32 MiB)

// ---------------- workspace layout (bytes) ----------------
constexpr size_t NX  = (size_t)Bn * Sn * Dn;   // 8388608
constexpr size_t NW1 = (size_t)Hn * Dn;        // 4194304
constexpr size_t NW2 = (size_t)Hn * Hn;        // 16777216
constexpr size_t NRS = (size_t)Bn * Sn * Hn;   // 33554432

constexpr size_t OFF_XH   = 0;                         // 16 MB (live: G1,G3)
constexpr size_t OFF_XL   = OFF_XH  + 2 * NX;          // 16 MB (G1; then BUF, then DWNW)
constexpr size_t OFF_W1H  = OFF_XL  + 2 * NX;          // 8 MB  (G1; then BUF, then UPW)
constexpr size_t OFF_W1L  = OFF_W1H + 2 * NW1;         // 8 MB  (G1; then BUF, then MODW)
constexpr size_t OFF_W2H  = OFF_W1L + 2 * NW1;         // 32 MB (G2)
constexpr size_t OFF_W2L  = OFF_W2H + 2 * NW2;         // 32 MB (G2)
constexpr size_t OFF_RSH  = OFF_W2L + 2 * NW2;         // 64 MB (G1->G2; then HBUF)
constexpr size_t OFF_RSL  = OFF_RSH + 2 * NRS;         // 64 MB (G1->G2)
constexpr size_t OFF_HIST = OFF_RSL + 2 * NRS;         // 8 x 8192 u32  (zeroed)
constexpr size_t OFF_HIST2= OFF_HIST + (size_t)Bn * 8192 * 4;   // 8 x 16384 u32 (zeroed)
constexpr size_t OFF_HMAX = OFF_HIST2+ (size_t)Bn * 16384 * 4;  // 8 x 4096 u32  (zeroed)
constexpr size_t OFF_META = OFF_HMAX + (size_t)Bn * Hn * 4;     // 1024 u32      (zeroed)
constexpr size_t OFF_BSEL = OFF_META + 4096;           // 8 x 4096 f32
constexpr size_t OFF_MASK = OFF_BSEL + (size_t)Bn * Hn * 4;     // 8 x 4096 u32
constexpr size_t WS_SMALL = OFF_MASK + (size_t)Bn * Hn * 4;     // ~241.2 MB
constexpr size_t ZERO_BYTES = OFF_BSEL - OFF_HIST;     // hist + hist2 + hmax + meta
// BUF lives in the dead XL/W1H/W1L span (exactly 32 MiB) during G2..refine
constexpr size_t OFF_BUF  = OFF_XL;

// ---------------- helpers ----------------
__device__ __forceinline__ ushort f2bf(float f) {        // fp32 -> bf16 RNE
  uint32 u = __float_as_uint(f);
  u += 0x7fffu + ((u >> 16) & 1u);
  return (ushort)(u >> 16);
}
__device__ __forceinline__ float bf2f(ushort h) {
  return __uint_as_float(((uint32)h) << 16);
}
__device__ __forceinline__ uint32 skey(float v) {        // monotone fp32 -> u32 key
  uint32 u = __float_as_uint(v);
  return (u & 0x80000000u) ? ~u : (u | 0x80000000u);
}
__device__ __forceinline__ uint32 ekey(uint32 key) {     // 27-bit compact key
  if (key <= SKBASE) return 0u;
  uint32 d = key - SKBASE;
  return d > EMAX ? EMAX : d;
}
__device__ __forceinline__ void g2l(const ushort* src, ushort* dst) {
  __builtin_amdgcn_global_load_lds((gcptr)src, (lptr)dst, 16, 0, 0);
}
// stage one 128x32 bf16 tile (8 KB) via global_load_lds width=16.
// LDS dest is wave-uniform base + lane*16 (m104/m108 rule) -> unpadded row-major layout.
__device__ __forceinline__ void stage_tile(ushort* lds, const ushort* gbase, int ldg, int tid) {
  const int w = tid >> 6;
  const int c0 = tid, c1 = tid + 256;
  g2l(gbase + (size_t)(c0 >> 2) * ldg + (c0 & 3) * 8, lds + (size_t)(w * 64) * 8);
  g2l(gbase + (size_t)(c1 >> 2) * ldg + (c1 & 3) * 8, lds + (size_t)(256 + w * 64) * 8);
}
// same, but per-row source select between mod_w / up_w via mask (per-lane global address ok)
__device__ __forceinline__ void stage_tile_sel(ushort* lds, const ushort* upw,
                                               const ushort* modw, const uint32* bm,
                                               int n0, int k0, int ldg, int tid) {
  const int w = tid >> 6;
  const int c0 = tid, c1 = tid + 256;
  const int r0 = n0 + (c0 >> 2), r1 = n0 + (c1 >> 2);
  const ushort* s0 = (bm[r0] ? modw : upw) + (size_t)r0 * ldg + k0 + (c0 & 3) * 8;
  const ushort* s1 = (bm[r1] ? modw : upw) + (size_t)r1 * ldg + k0 + (c1 & 3) * 8;
  g2l(s0, lds + (size_t)(w * 64) * 8);
  g2l(s1, lds + (size_t)(256 + w * 64) * 8);
}

// ---------------- conversion kernels ----------------
__global__ __launch_bounds__(256) void cvt_split_k(const float4* __restrict__ x,
                                                   ushort* __restrict__ hi,
                                                   ushort* __restrict__ lo, int n4) {
  int stride = gridDim.x * 256;
  for (int i = blockIdx.x * 256 + threadIdx.x; i < n4; i += stride) {
    float4 v = x[i];
    ushort h0 = f2bf(v.x), h1 = f2bf(v.y), h2 = f2bf(v.z), h3 = f2bf(v.w);
    ushort4 hv; hv.x = h0; hv.y = h1; hv.z = h2; hv.w = h3;
    *(ushort4*)(hi + (size_t)i * 4) = hv;
    ushort4 lv;
    lv.x = f2bf(v.x - bf2f(h0)); lv.y = f2bf(v.y - bf2f(h1));
    lv.z = f2bf(v.z - bf2f(h2)); lv.w = f2bf(v.w - bf2f(h3));
    *(ushort4*)(lo + (size_t)i * 4) = lv;
  }
}
__global__ __launch_bounds__(256) void cvt_single_k(const float4* __restrict__ x,
                                                    ushort* __restrict__ hi, int n4) {
  int stride = gridDim.x * 256;
  for (int i = blockIdx.x * 256 + threadIdx.x; i < n4; i += stride) {
    float4 v = x[i];
    ushort4 hv; hv.x = f2bf(v.x); hv.y = f2bf(v.y); hv.z = f2bf(v.z); hv.w = f2bf(v.w);
    *(ushort4*)(hi + (size_t)i * 4) = hv;
  }
}
__global__ __launch_bounds__(256) void zero_out_k(float* __restrict__ o, int n) {
  int i = blockIdx.x * 256 + threadIdx.x;
  if (i < n) o[i] = 0.f;
}

// ---------------- GEMM: C[m,n] = sum_k A[m,k]*B[n,k] (+epilogue) ----------------
// 128x128 tile, BK=32, 4 waves (2x2 of 64x64), mfma_f32_16x16x32_bf16.
// SPLIT: A,B given as hi+lo bf16 pairs; acc += Ah*Bh + Al*Bh + Ah*Bl (near-fp32 product).
// Pass order P1,P3,P2 with scoped just-in-time fragment loads keeps peak live
// fragments at 96 regs; __launch_bounds__(256,3) targets 3 waves/SIMD so a
// third co-resident block can compute through another block's barrier drain.
// SELB:  B rows staged per-row from (mask ? modw : upw).
constexpr int EPI_RELU = 0;    // out: rs_hi/rs_lo bf16 split of relu(acc+bias[n])
constexpr int EPI_SCORE = 1;   // hist/colmax + windowed key append of acc+bias[n]
constexpr int EPI_SILU = 2;    // out: bf16 silu(acc+bias[n]), batched via blockIdx.z
constexpr int EPI_F32 = 3;     // out: f32 acc+bias[n]

template <bool SPLIT, bool SELB, int EPI>
__global__ __launch_bounds__(256, SPLIT ? 3 : 2) void gemm_bt(
    const ushort* __restrict__ Ah, const ushort* __restrict__ Al,
    const ushort* __restrict__ Bh, const ushort* __restrict__ Bl,
    const uint32* __restrict__ bmask,
    int N, int K, long long a_bs, long long o_bs, long long bias_bs,
    const float* __restrict__ bias,
    void* __restrict__ outp, void* __restrict__ out2p,
    uint32* __restrict__ hist, uint32* __restrict__ hmax,
    uint32* __restrict__ buf, uint32* __restrict__ cnt) {
  static_assert(EPI != EPI_SCORE || SPLIT, "score path is split");
  __shared__ __align__(16) ushort lds[SPLIT ? 16384 : 8192];
  ushort* As = lds;
  ushort* Bs = lds + (SPLIT ? 8192 : 4096);

  const int tid = threadIdx.x;
  const int w = tid >> 6, l = tid & 63;
  const int wm = (w >> 1) << 6, wn = (w & 1) << 6;
  const int lm = l & 15, lq = l >> 4;
  const int m0 = blockIdx.y << 7, n0 = blockIdx.x << 7;
  const int z = blockIdx.z;

  const ushort* pAh = Ah + (size_t)z * a_bs + (size_t)m0 * K;
  const ushort* pAl = SPLIT ? Al + (size_t)z * a_bs + (size_t)m0 * K : nullptr;
  const ushort* pBh = SELB ? nullptr : Bh + (size_t)n0 * K;
  const ushort* pBl = (SPLIT && !SELB) ? Bl + (size_t)n0 * K : nullptr;
  const uint32* bm = SELB ? bmask + (size_t)z * Hn : nullptr;

  floatx4 acc[4][4];
#pragma unroll
  for (int i = 0; i < 4; i++)
#pragma unroll
    for (int j = 0; j < 4; j++) acc[i][j] = floatx4{0.f, 0.f, 0.f, 0.f};

  for (int k0 = 0; k0 < K; k0 += 32) {
    stage_tile(As, pAh + k0, K, tid);
    if constexpr (SELB)
      stage_tile_sel(Bs, Bh, Bl, bm, n0, k0, K, tid);
    else
      stage_tile(Bs, pBh + k0, K, tid);
    if constexpr (SPLIT) {
      stage_tile(As + 4096, pAl + k0, K, tid);
      stage_tile(Bs + 4096, pBl + k0, K, tid);
    }
    __syncthreads();
    short8 afh[4], bfh[4];
#pragma unroll
    for (int i = 0; i < 4; i++)
      afh[i] = *(const short8*)&As[(wm + i * 16 + lm) * 32 + lq * 8];
#pragma unroll
    for (int i = 0; i < 4; i++)
      bfh[i] = *(const short8*)&Bs[(wn + i * 16 + lm) * 32 + lq * 8];
#pragma unroll
    for (int mi = 0; mi < 4; mi++)
#pragma unroll
      for (int ni = 0; ni < 4; ni++)
        acc[mi][ni] = __builtin_amdgcn_mfma_f32_16x16x32_bf16(afh[mi], bfh[ni], acc[mi][ni], 0, 0, 0);
    if constexpr (SPLIT) {
      {  // P3: Al*Bh (bfh still live, afl scoped)
        short8 afl[4];
#pragma unroll
        for (int i = 0; i < 4; i++)
          afl[i] = *(const short8*)&As[4096 + (wm + i * 16 + lm) * 32 + lq * 8];
#pragma unroll
        for (int mi = 0; mi < 4; mi++)
#pragma unroll
          for (int ni = 0; ni < 4; ni++)
            acc[mi][ni] = __builtin_amdgcn_mfma_f32_16x16x32_bf16(afl[mi], bfh[ni], acc[mi][ni], 0, 0, 0);
      }
      {  // P2: Ah*Bl (bfh dead, bfl reuses its slots)
        short8 bfl[4];
#pragma unroll
        for (int i = 0; i < 4; i++)
          bfl[i] = *(const short8*)&Bs[4096 + (wn + i * 16 + lm) * 32 + lq * 8];
#pragma unroll
        for (int mi = 0; mi < 4; mi++)
#pragma unroll
          for (int ni = 0; ni < 4; ni++)
            acc[mi][ni] = __builtin_amdgcn_mfma_f32_16x16x32_bf16(afh[mi], bfl[ni], acc[mi][ni], 0, 0, 0);
      }
    }
    __syncthreads();
  }

  // ---- epilogue. D layout: row m = wm+mi*16+lq*4+r, col n = wn+ni*16+lm (m89/m91) ----
  if constexpr (EPI == EPI_RELU) {
    ushort* rh = (ushort*)outp;
    ushort* rl = (ushort*)out2p;
#pragma unroll
    for (int mi = 0; mi < 4; mi++)
#pragma unroll
      for (int ni = 0; ni < 4; ni++) {
        int gm = m0 + wm + mi * 16 + lq * 4;
        int gn = n0 + wn + ni * 16 + lm;
        float bnv = bias[gn];
#pragma unroll
        for (int r = 0; r < 4; r++) {
          float v = fmaxf(acc[mi][ni][r] + bnv, 0.f);
          ushort h = f2bf(v);
          size_t o = (size_t)(gm + r) * N + gn;
          rh[o] = h;
          rl[o] = f2bf(v - bf2f(h));
        }
      }
  } else if constexpr (EPI == EPI_SILU) {
    ushort* o = (ushort*)outp + (size_t)z * o_bs;
    const float* bb = bias + (size_t)z * bias_bs;
#pragma unroll
    for (int mi = 0; mi < 4; mi++)
#pragma unroll
      for (int ni = 0; ni < 4; ni++) {
        int gm = m0 + wm + mi * 16 + lq * 4;
        int gn = n0 + wn + ni * 16 + lm;
        float bnv = bb[gn];
#pragma unroll
        for (int r = 0; r < 4; r++) {
          float v = acc[mi][ni][r] + bnv;
          float s = v / (1.f + __expf(-v));
          o[(size_t)(gm + r) * N + gn] = f2bf(s);
        }
      }
  } else if constexpr (EPI == EPI_F32) {
    float* o = (float*)outp;
#pragma unroll
    for (int mi = 0; mi < 4; mi++)
#pragma unroll
      for (int ni = 0; ni < 4; ni++) {
        int gm = m0 + wm + mi * 16 + lq * 4;
        int gn = n0 + wn + ni * 16 + lm;
        float bnv = bias[gn];
#pragma unroll
        for (int r = 0; r < 4; r++)
          o[(size_t)(gm + r) * N + gn] = acc[mi][ni][r] + bnv;
      }
  } else {  // EPI_SCORE: tiles dead -> overlay 8192-bin u32 LDS histogram (32 KB)
    uint32* hs = (uint32*)lds;
    for (int i = tid; i < 8192; i += 256) hs[i] = 0;
    __syncthreads();
    const int batch = m0 >> 10;  // 128-row blocks never straddle a batch
    uint32 cntl = 0;             // lane's in-window count
#pragma unroll
    for (int ni = 0; ni < 4; ni++) {
      int gn = n0 + wn + ni * 16 + lm;
      float bnv = bias[gn];
      float vmax = -3.4e38f;
#pragma unroll
      for (int mi = 0; mi < 4; mi++) {
#pragma unroll
        for (int r = 0; r < 4; r++) {
          float v = acc[mi][ni][r] + bnv;
          uint32 e = ekey(skey(v));
          uint32 bk = e >> 14;
          atomicAdd(&hs[bk], 1u);
          if (bk >= WLO && bk <= WHI) cntl++;
          vmax = fmaxf(vmax, v);
        }
      }
      atomicMax(&hmax[batch * Hn + gn], skey(vmax));  // all 16 values share column gn
    }
    __syncthreads();
    for (int i = tid; i < 8192; i += 256) {
      uint32 c = hs[i];
      if (c) atomicAdd(&hist[batch * 8192 + i], c);
    }
    __syncthreads();
    // block-aggregated append of in-window keys: one global atomic per block
    hs[tid] = cntl;
    __syncthreads();
    if (tid == 0) {
      uint32 run = 0;
      for (int i = 0; i < 256; i++) { uint32 t = hs[i]; hs[i] = run; run += t; }
      hs[256] = atomicAdd(&cnt[batch], run);
    }
    __syncthreads();
    uint32 off = hs[256] + hs[tid];
    uint32* bb = buf + (size_t)batch * CAP;
#pragma unroll
    for (int ni = 0; ni < 4; ni++) {
      int gn = n0 + wn + ni * 16 + lm;
      float bnv = bias[gn];
#pragma unroll
      for (int mi = 0; mi < 4; mi++) {
#pragma unroll
        for (int r = 0; r < 4; r++) {
          float v = acc[mi][ni][r] + bnv;
          uint32 e = ekey(skey(v));
          uint32 bk = e >> 14;
          if (bk >= WLO && bk <= WHI) {
            if (off < CAP) bb[off] = e;
            off++;
          }
        }
      }
    }
  }
}

// ---------------- selection kernels ----------------
// meta[0..7]=threshold key (skey space), meta[8..15]=bucket j, meta[16..23]=need-in-bucket,
// meta[32..39]=per-batch append counters (zeroed with the hist block)
__global__ __launch_bounds__(256) void select1_k(const uint32* __restrict__ hist,
                                                 uint32* __restrict__ meta) {
  int b = blockIdx.x;
  const uint32* h = hist + b * 8192;
  __shared__ uint32 ps[256];
  uint32 s = 0;
  int base = threadIdx.x * 32;
  for (int i = 0; i < 32; i++) s += h[base + i];
  ps[threadIdx.x] = s;
  __syncthreads();
  if (threadIdx.x == 0) {
    uint32 cum = 0, need = 1;
    int j = 0;
    for (int c = 255; c >= 0; c--) {
      if (cum + ps[c] >= KTOP) {
        for (int i = c * 32 + 31;; i--) {
          uint32 hv = h[i];
          if (cum + hv >= KTOP) { j = i; need = KTOP - cum; break; }
          cum += hv;
        }
        break;
      }
      cum += ps[c];
    }
    meta[8 + b] = (uint32)j;
    meta[16 + b] = need;
    meta[b] = SKBASE + ((uint32)j << 14);  // bucket-edge fallback; select2 refines
  }
}

// build boundary-bucket remainder histogram from the windowed append buffer
__global__ __launch_bounds__(256) void refine_buf_k(const uint32* __restrict__ buf,
                                                    const uint32* __restrict__ meta,
                                                    uint32* __restrict__ hist2) {
  const uint32* cnt = meta + 32;
  size_t stride = (size_t)gridDim.x * 256;
  for (int b = 0; b < Bn; b++) {
    uint32 n = cnt[b] < CAP ? cnt[b] : CAP;
    uint32 j = meta[8 + b];
    const uint32* bb = buf + (size_t)b * CAP;
    for (size_t i = (size_t)blockIdx.x * 256 + threadIdx.x; i < n; i += stride) {
      uint32 e = bb[i];
      if ((e >> 14) == j) atomicAdd(&hist2[(size_t)b * 16384 + (e & 0x3FFFu)], 1u);
    }
  }
}

__global__ __launch_bounds__(256) void select2_k(const uint32* __restrict__ hist2,
                                                 uint32* __restrict__ meta) {
  int b = blockIdx.x;
  const uint32* h2 = hist2 + (size_t)b * 16384;
  __shared__ uint32 ps[256];
  uint32 s = 0;
  const uint32* p = h2 + (size_t)threadIdx.x * 64;
  for (int i = 0; i < 64; i += 4) {
    uint4 v = *(const uint4*)(p + i);
    s += v.x + v.y + v.z + v.w;
  }
  ps[threadIdx.x] = s;
  __syncthreads();
  if (threadIdx.x == 0) {
    uint32 j = meta[8 + b];
    uint32 valid = (j >= WLO && j <= WHI && meta[32 + b] <= CAP) ? 1u : 0u;
    if (valid) {
      uint32 need = meta[16 + b];
      uint32 cum = 0;
      int c = 255;
      for (; c > 0; c--) {
        if (cum + ps[c] >= need) break;
        cum += ps[c];
      }
      uint32 rem = 0;
      for (int i = 63; i >= 0; i--) {
        uint32 hv = h2[c * 64 + i];
        if (cum + hv >= need) { rem = (uint32)(c * 64 + i); break; }
        cum += hv;
      }
      meta[b] = SKBASE + (j << 14) + rem;  // exact 32-bit threshold
    }
    // else: keep select1's bucket-edge fallback
  }
}

__global__ __launch_bounds__(256) void mask_k(const uint32* __restrict__ hmax,
                                              const uint32* __restrict__ meta,
                                              const float* __restrict__ modb,
                                              const float* __restrict__ upb,
                                              uint32* __restrict__ mask,
                                              float* __restrict__ bsel) {
  int i = blockIdx.x * 256 + threadIdx.x;  // Bn*Hn = 32768
  int b = i >> 12, h = i & 4095;
  bool m = hmax[i] >= meta[b];
  mask[i] = m ? 1u : 0u;
  bsel[i] = m ? modb[h] : upb[h];
}

// ---------------- launch ----------------
extern "C" void kernel_launch(void* const* d_in, const int* in_sizes, int n_in,
                              void* d_out, int out_size, void* d_ws, size_t ws_size,
                              hipStream_t stream) {
  (void)in_sizes; (void)n_in;
  const float* x    = (const float*)d_in[0];
  const float* up_w = (const float*)d_in[1];
  const float* up_b = (const float*)d_in[2];
  const float* g_w1 = (const float*)d_in[3];
  const float* g_b1 = (const float*)d_in[4];
  const float* g_w2 = (const float*)d_in[5];
  const float* g_b2 = (const float*)d_in[6];
  const float* mod_w= (const float*)d_in[7];
  const float* mod_b= (const float*)d_in[8];
  const float* dw   = (const float*)d_in[9];
  const float* db   = (const float*)d_in[10];
  float* out = (float*)d_out;

  if (ws_size < WS_SMALL) {  // diagnosable clean failure instead of OOB fault
    zero_out_k<<<(out_size + 255) / 256, 256, 0, stream>>>(out, out_size);
    return;
  }

  char* ws = (char*)d_ws;
  ushort* XH  = (ushort*)(ws + OFF_XH);
  ushort* XL  = (ushort*)(ws + OFF_XL);
  ushort* W1H = (ushort*)(ws + OFF_W1H);
  ushort* W1L = (ushort*)(ws + OFF_W1L);
  ushort* W2H = (ushort*)(ws + OFF_W2H);
  ushort* W2L = (ushort*)(ws + OFF_W2L);
  ushort* RSH = (ushort*)(ws + OFF_RSH);
  ushort* RSL = (ushort*)(ws + OFF_RSL);
  uint32* HIST = (uint32*)(ws + OFF_HIST);
  uint32* HIST2= (uint32*)(ws + OFF_HIST2);
  uint32* HMAX = (uint32*)(ws + OFF_HMAX);
  uint32* META = (uint32*)(ws + OFF_META);
  float*  BSEL = (float*)(ws + OFF_BSEL);
  uint32* MASK = (uint32*)(ws + OFF_MASK);
  uint32* BUF  = (uint32*)(ws + OFF_BUF);
  ushort* UPW  = W1H;   // reuse: W1/BUF dead after refine
  ushort* MODW = W1L;
  ushort* DWNW = XL;
  ushort* HBUF = RSH;   // reuse: RSH dead after G2

  hipMemsetAsync(ws + OFF_HIST, 0, ZERO_BYTES, stream);

  cvt_split_k<<<1024, 256, 0, stream>>>((const float4*)x, XH, XL, (int)(NX / 4));
  cvt_split_k<<<1024, 256, 0, stream>>>((const float4*)g_w1, W1H, W1L, (int)(NW1 / 4));
  cvt_split_k<<<2048, 256, 0, stream>>>((const float4*)g_w2, W2H, W2L, (int)(NW2 / 4));

  // G1: rs = relu(X*W1^T + b1), split-bf16, split store
  gemm_bt<true, false, EPI_RELU><<<dim3(Hn / 128, (Bn * Sn) / 128, 1), 256, 0, stream>>>(
      XH, XL, W1H, W1L, nullptr, Hn, Dn, 0, 0, 0, g_b1, RSH, RSL,
      nullptr, nullptr, nullptr, nullptr);
  // G2: scores = rs*W2^T + b2; fused hist/colmax + windowed key append (BUF overlays XL/W1)
  gemm_bt<true, false, EPI_SCORE><<<dim3(Hn / 128, (Bn * Sn) / 128, 1), 256, 0, stream>>>(
      RSH, RSL, W2H, W2L, nullptr, Hn, Hn, 0, 0, 0, g_b2, nullptr, nullptr,
      HIST, HMAX, BUF, META + 32);
  select1_k<<<Bn, 256, 0, stream>>>(HIST, META);
  refine_buf_k<<<512, 256, 0, stream>>>(BUF, META, HIST2);
  select2_k<<<Bn, 256, 0, stream>>>(HIST2, META);
  mask_k<<<(Bn * Hn) / 256, 256, 0, stream>>>(HMAX, META, mod_b, up_b, MASK, BSEL);

  // lazy conversions into regions dead after refine (overwrite BUF)
  cvt_single_k<<<1024, 256, 0, stream>>>((const float4*)up_w, UPW, (int)(NW1 / 4));
  cvt_single_k<<<1024, 256, 0, stream>>>((const float4*)mod_w, MODW, (int)(NW1 / 4));
  cvt_single_k<<<1024, 256, 0, stream>>>((const float4*)dw, DWNW, (int)(NW1 / 4));

  // G3: h = silu(X * sel_w^T + sel_b), B rows selected per-lane at staging time
  gemm_bt<false, true, EPI_SILU><<<dim3(Hn / 128, Sn / 128, Bn), 256, 0, stream>>>(
      XH, nullptr, UPW, MODW, MASK, Hn, Dn,
      (long long)Sn * Dn, (long long)Sn * Hn, (long long)Hn,
      BSEL, HBUF, nullptr, nullptr, nullptr, nullptr, nullptr);
  // G4: out = h * down_w^T + down_b (fp32 out)
  gemm_bt<false, false, EPI_F32><<<dim3(Dn / 128, (Bn * Sn) / 128, 1), 256, 0, stream>>>(
      HBUF, nullptr, DWNW, nullptr, nullptr, Dn, Hn, 0, 0, 0, db, out, nullptr,
      nullptr, nullptr, nullptr, nullptr);
}